// Round 8
// baseline (111.605 us; speedup 1.0000x reference)
//
#include <hip/hip_runtime.h>

#define TPB 256
#define R 8           // source points per lane (40 VGPRs live - no fission risk)
#define CHUNKS 64     // CH targets per block
#define CH 256        // N / CHUNKS
#define BATCH 8       // targets per SMEM batch (4 x s_load_dwordx8)
// N=16384 fixed for this problem: SB = N/(TPB*R) = 8; grid = 2*SB*CHUNKS = 1024

constexpr int N = 16384;

typedef __attribute__((ext_vector_type(8))) float f8;

// AoS {x,y,z,|p|^2} for source-side (per-lane coalesced loads) and
// SoA X[N]|Y[N]|Z[N]|W[N] for target-side (wave-uniform s_load batches).
__global__ __launch_bounds__(TPB) void prep_kernel(
        const float* __restrict__ a, const float* __restrict__ b,
        float4* __restrict__ srcA, float4* __restrict__ srcB,
        float* __restrict__ soaA, float* __restrict__ soaB,
        unsigned* __restrict__ pmins, float* __restrict__ acc,
        unsigned* __restrict__ cnt) {
    int idx = blockIdx.x * blockDim.x + threadIdx.x;
    if (idx < N) {
        float x = a[3 * idx], y = a[3 * idx + 1], z = a[3 * idx + 2];
        float w = x * x + y * y + z * z;
        srcA[idx] = make_float4(x, y, z, w);
        soaA[idx] = x; soaA[idx + N] = y; soaA[idx + 2 * N] = z; soaA[idx + 3 * N] = w;
    } else if (idx < 2 * N) {
        int i = idx - N;
        float x = b[3 * i], y = b[3 * i + 1], z = b[3 * i + 2];
        float w = x * x + y * y + z * z;
        srcB[i] = make_float4(x, y, z, w);
        soaB[i] = x; soaB[i + N] = y; soaB[i + 2 * N] = z; soaB[i + 3 * N] = w;
    }
    if (idx < 2 * N) pmins[idx] = 0xFFFFFFFFu;
    if (idx == 0) { acc[0] = 0.0f; cnt[0] = 0u; }
}

// min_t(|s-t|^2) = |s|^2 + min_t(|t|^2 - 2 s.t)
// Targets arrive in SGPRs via s_load_dwordx8 (scalar pipe, double-buffered);
// VALU stream is pure v_fma (1 SGPR operand/inst) + v_min3. No LDS at all.
__global__ __launch_bounds__(TPB, 4) void minpass_kernel(
        const float4* __restrict__ srcA, const float4* __restrict__ srcB,
        const float* __restrict__ soaA, const float* __restrict__ soaB,
        unsigned* __restrict__ pmins) {
    const int SB = N / (TPB * R);   // 8
    int b = blockIdx.x;
    int dir = b / (SB * CHUNKS);
    int rem = b % (SB * CHUNKS);
    int chunk = rem / SB;
    int sblk = rem % SB;
    const float4* __restrict__ src = dir ? srcB : srcA;
    const float* __restrict__ tb = dir ? soaA : soaB;

    float ax[R], ay[R], az[R], sw[R], m[R];
    int s0 = sblk * TPB * R + threadIdx.x;  // stride-TPB between r's: coalesced
#pragma unroll
    for (int r = 0; r < R; ++r) {
        float4 s = src[s0 + r * TPB];
        ax[r] = -2.0f * s.x; ay[r] = -2.0f * s.y; az[r] = -2.0f * s.z;
        sw[r] = s.w; m[r] = __builtin_inff();
    }

    const float* p = tb + chunk * CH;  // X base; Y/Z/W at +64/128/192 KB imm

    f8 X0, Y0, Z0, W0, X1, Y1, Z1, W1;
// 4 scalar loads for one batch of 8 targets (components at fixed 64KB strides)
#define LOADB(i, P) asm volatile( \
    "s_load_dwordx8 %0, %4, 0x0\n\t" \
    "s_load_dwordx8 %1, %4, 0x10000\n\t" \
    "s_load_dwordx8 %2, %4, 0x20000\n\t" \
    "s_load_dwordx8 %3, %4, 0x30000" \
    : "=s"(X##i), "=s"(Y##i), "=s"(Z##i), "=s"(W##i) : "s"(P))
// full drain; "+s" ties force all uses to stay after the wait
#define WAITB(i) asm volatile("s_waitcnt lgkmcnt(0)" \
    : "+s"(X##i), "+s"(Y##i), "+s"(Z##i), "+s"(W##i))
#define COMPUTEB(i) \
    _Pragma("unroll") \
    for (int t = 0; t < BATCH; t += 2) { \
        float px0 = X##i[t], py0 = Y##i[t], pz0 = Z##i[t], pw0 = W##i[t]; \
        float px1 = X##i[t+1], py1 = Y##i[t+1], pz1 = Z##i[t+1], pw1 = W##i[t+1]; \
        _Pragma("unroll") \
        for (int r = 0; r < R; ++r) { \
            float d0 = fmaf(ax[r], px0, fmaf(ay[r], py0, fmaf(az[r], pz0, pw0))); \
            float d1 = fmaf(ax[r], px1, fmaf(ay[r], py1, fmaf(az[r], pz1, pw1))); \
            m[r] = fminf(m[r], fminf(d0, d1)); \
        } \
    }

    LOADB(0, p); p += BATCH;
#pragma unroll 1
    for (int jb = 0; jb < CH / (2 * BATCH); ++jb) {  // 16 iters x 2 batches
        WAITB(0);
        LOADB(1, p); p += BATCH;   // b1 latency hides behind compute(b0)
        COMPUTEB(0);
        WAITB(1);
        LOADB(0, p); p += BATCH;   // final iter prefetches past chunk: mapped ws, unused
        COMPUTEB(1);
    }

    // nonneg floats monotone under unsigned compare -> uint atomicMin
#pragma unroll
    for (int r = 0; r < R; ++r)
        atomicMin(&pmins[dir * N + s0 + r * TPB], __float_as_uint(m[r] + sw[r]));
}

// 32 blocks x 256 threads: each thread sums one uint4; atomicAdd + gated out.
__global__ __launch_bounds__(TPB) void finalize_kernel(
        const uint4* __restrict__ pmins, float* __restrict__ acc,
        unsigned* __restrict__ cnt, float* __restrict__ out, int nblocks) {
    int i = blockIdx.x * TPB + threadIdx.x;  // i-th uint4, total 2N/4
    uint4 v = pmins[i];
    float sum = __uint_as_float(v.x) + __uint_as_float(v.y)
              + __uint_as_float(v.z) + __uint_as_float(v.w);
    for (int off = 32; off > 0; off >>= 1)
        sum += __shfl_down(sum, off, 64);
    __shared__ float wsum[TPB / 64];
    int lane = threadIdx.x & 63, wid = threadIdx.x >> 6;
    if (lane == 0) wsum[wid] = sum;
    __syncthreads();
    if (threadIdx.x == 0) {
        float t = 0.0f;
        for (int w = 0; w < TPB / 64; ++w) t += wsum[w];
        atomicAdd(acc, t);
        __threadfence();
        unsigned old = atomicAdd(cnt, 1u);
        if (old == (unsigned)(nblocks - 1)) {
            float a0 = atomicAdd(acc, 0.0f);  // device-scope coherent read
            out[0] = a0 / (float)(2 * N);
        }
    }
}

extern "C" void kernel_launch(void* const* d_in, const int* in_sizes, int n_in,
                              void* d_out, int out_size, void* d_ws, size_t ws_size,
                              hipStream_t stream) {
    const float* a = (const float*)d_in[0];
    const float* b = (const float*)d_in[1];
    float* out = (float*)d_out;
    char* ws = (char*)d_ws;
    float* acc = (float*)ws;                      // 1 float
    unsigned* cnt = (unsigned*)(ws + 8);          // 1 uint
    float4* srcA = (float4*)(ws + 256);           // N float4
    float4* srcB = srcA + N;                      // N float4
    float* soaA = (float*)(srcB + N);             // 4N floats
    float* soaB = soaA + 4 * N;                   // 4N floats
    unsigned* pmins = (unsigned*)(soaB + 4 * N);  // 2N uints (also absorbs tail prefetch)

    prep_kernel<<<(2 * N + TPB - 1) / TPB, TPB, 0, stream>>>(
        a, b, srcA, srcB, soaA, soaB, pmins, acc, cnt);
    int SB = N / (TPB * R);
    minpass_kernel<<<2 * SB * CHUNKS, TPB, 0, stream>>>(srcA, srcB, soaA, soaB, pmins);
    int fblocks = (2 * N / 4) / TPB;  // 32
    finalize_kernel<<<fblocks, TPB, 0, stream>>>(
        (const uint4*)pmins, acc, cnt, out, fblocks);
}